// Round 5
// baseline (257.387 us; speedup 1.0000x reference)
//
#include <hip/hip_runtime.h>

#define BATCH 512
#define V 6890
#define NJ 24
#define VH (V/2)   // 3445 float2 per feature row

#define SD_N (V*30)
#define VT_N (V*3)
#define W_N  (V*24)
#define TOT_PK (SD_N+VT_N+W_N)   // 392730 floats
#define PREP_BLOCKS ((TOT_PK+255)/256)   // 1535

// workspace layout (float indices)
// A layout: 128 groups of 4 batches: off = (b>>2)*1152 + n*48 + (b&3)*12 + j
#define A_OFF   0
#define BS_OFF  147456     // BATCH*16 scalars {b0, b0*beta[1..10], transl[0..2], pad}
#define JT_OFF  155648     // 72  = Jr @ v_template
#define JS_OFF  155720     // 720 = Jr @ shapedirs
#define PK_OFF  156672     // transposed fp32, rows stride V:
                           //   sd row j at j*V; vt row k at (30+k)*V; W row n at (33+n)*V

__device__ const int d_par[NJ] = {-1,0,0,0,1,2,3,4,5,6,7,8,9,9,9,12,13,14,16,17,18,19,20,21};
// kinematic tree by depth level: joints and their parents (parents always in earlier level)
__device__ const int lvlJ[8][5] = {{1,2,3,0,0},{4,5,6,0,0},{7,8,9,0,0},{10,11,12,13,14},
                                   {15,16,17,0,0},{18,19,0,0,0},{20,21,0,0,0},{22,23,0,0,0}};
__device__ const int lvlP[8][5] = {{0,0,0,0,0},{1,2,3,0,0},{4,5,6,0,0},{7,8,9,9,9},
                                   {12,13,14,0,0},{16,17,0,0,0},{18,19,0,0,0},{20,21,0,0,0}};
__device__ const int lvlN[8] = {3,3,3,5,3,2,2,2};

// -------- fused: transpose per-vertex data + joint-regressor contraction --------
__global__ __launch_bounds__(256) void prepjr_k(
    const float* __restrict__ sd, const float* __restrict__ vt,
    const float* __restrict__ W, const float* __restrict__ Jr,
    float* __restrict__ dst, float* __restrict__ JTo, float* __restrict__ JSo)
{
  const int bx = blockIdx.x;
  const int t = threadIdx.x;
  if (bx < PREP_BLOCKS){
    int i = bx*256 + t;
    if (i >= TOT_PK) return;
    float val;
    if (i < SD_N){ int j=i/V, v=i-j*V; val = sd[v*30+j]; }
    else if (i < SD_N+VT_N){ int o=i-SD_N; int j=o/V, v=o-j*V; val = vt[v*3+j]; }
    else { int o=i-SD_N-VT_N; int j=o/V, v=o-j*V; val = W[v*24+j]; }
    dst[i] = val;
  } else {
    const int idx = bx - PREP_BLOCKS;   // 0..791
    const int j = idx/33, c = idx-33*(idx/33);
    float acc = 0.f;
    for (int v=t; v<V; v+=256){
      float x = (c<3) ? vt[v*3+c] : sd[v*30+(c-3)];
      acc = fmaf(Jr[j*V+v], x, acc);
    }
    __shared__ float red[256];
    red[t]=acc; __syncthreads();
    for (int s=128;s>0;s>>=1){ if(t<s) red[t]+=red[t+s]; __syncthreads(); }
    if (t==0){
      if (c<3) JTo[j*3+c]=red[0];
      else {
        int ii=c-3, k=ii/10, l=ii-10*(ii/10);
        JSo[(j*3+k)*10+l] = red[0];
      }
    }
  }
}

// -------- per-batch: joints, rodrigues, level-parallel chain, A (grouped) --------
__global__ __launch_bounds__(64) void batch_k(
    const float* __restrict__ betas, const float* __restrict__ body_pose,
    const float* __restrict__ go, const float* __restrict__ transl,
    const float* __restrict__ JT, const float* __restrict__ JS,
    float* __restrict__ A, float* __restrict__ bsc, float* __restrict__ jout)
{
  const int b = blockIdx.x;
  const int t = threadIdx.x;
  __shared__ float lb[11];
  __shared__ float lJ[72];
  __shared__ float lR[NJ*9];
  __shared__ float lL[NJ*12];
  __shared__ float lW[NJ*12];
  if (t < 11) lb[t] = betas[b*11+t];
  __syncthreads();
  const float b0 = lb[0];
  for (int idx=t; idx<72; idx+=64){
    float s = JT[idx];
    #pragma unroll
    for (int l=0;l<10;l++) s = fmaf(lb[1+l], JS[idx*10+l], s);
    lJ[idx] = b0*s;
  }
  if (t==0) bsc[b*16] = b0;
  if (t>=1 && t<11) bsc[b*16+t] = b0*lb[t];
  if (t<3) bsc[b*16+11+t] = transl[b*3+t];
  if (t < NJ){
    float p0,p1,p2;
    if (t==0){ p0=go[b*3+0]; p1=go[b*3+1]; p2=go[b*3+2]; }
    else { int o=b*69+(t-1)*3; p0=body_pose[o]; p1=body_pose[o+1]; p2=body_pose[o+2]; }
    float a0=p0+1e-8f, a1=p1+1e-8f, a2=p2+1e-8f;
    float angle = sqrtf(a0*a0+a1*a1+a2*a2);
    float inv = 1.0f/angle;
    float rx=p0*inv, ry=p1*inv, rz=p2*inv;
    float sn = sinf(angle), cs = cosf(angle), mc = 1.0f-cs;
    float K[9] = {0.f,-rz,ry, rz,0.f,-rx, -ry,rx,0.f};
    float KK[9];
    #pragma unroll
    for (int r=0;r<3;r++)
      #pragma unroll
      for (int c=0;c<3;c++)
        KK[r*3+c] = K[r*3+0]*K[0+c] + K[r*3+1]*K[3+c] + K[r*3+2]*K[6+c];
    #pragma unroll
    for (int e=0;e<9;e++){
      float ident = (e==0||e==4||e==8)?1.0f:0.0f;
      lR[t*9+e] = ident + sn*K[e] + mc*KK[e];
    }
  }
  __syncthreads();
  for (int idx=t; idx<288; idx+=64){
    int j = idx/12, rc = idx-12*j, r = rc>>2, c = rc&3;
    float val;
    if (c<3) val = lR[j*9 + r*3 + c];
    else {
      int p = (j==0) ? 0 : d_par[j];
      val = (j==0) ? lJ[r] : (lJ[j*3+r] - lJ[p*3+r]);
    }
    lL[idx] = val;
  }
  __syncthreads();
  if (t<12) lW[t] = lL[t];
  __syncthreads();
  // level-parallel kinematic chain: 8 steps
  #pragma unroll
  for (int lev=0; lev<8; lev++){
    const int cnt = lvlN[lev];
    if (t < cnt*12){
      int jl = t/12, e = t-12*jl, r = e>>2, c = e&3;
      int j = lvlJ[lev][jl], p = lvlP[lev][jl];
      float s = lW[p*12+r*4+0]*lL[j*12+0+c]
              + lW[p*12+r*4+1]*lL[j*12+4+c]
              + lW[p*12+r*4+2]*lL[j*12+8+c];
      if (c==3) s += lW[p*12+r*4+3];
      lW[j*12+e] = s;
    }
    __syncthreads();
  }
  for (int idx=t; idx<72; idx+=64){
    int j=idx/3, k=idx-3*j;
    jout[b*72+idx] = lW[j*12+k*4+3];
  }
  const int g = b>>2, q = b&3;
  float* __restrict__ Ab = A + g*1152 + q*12;
  for (int idx=t; idx<288; idx+=64){
    int n=idx/12, rc=idx-12*n, r=rc>>2, c=rc&3;
    float val = lW[n*12+rc];
    if (c==3){
      val -= lW[n*12+r*4+0]*lJ[n*3+0] + lW[n*12+r*4+1]*lJ[n*3+1] + lW[n*12+r*4+2]*lJ[n*3+2];
    }
    Ab[n*48 + rc] = val;
  }
}

// -------- main LBS: 1 vertex-pair x 4 block-shared batches; w preloaded in VGPRs ------
__global__ __launch_bounds__(256, 4) void main_k(
    const float* __restrict__ A, const float* __restrict__ bsc,
    const float2* __restrict__ pk, float* __restrict__ out)
{
  const int vh = blockIdx.x*256 + threadIdx.x;
  if (vh >= VH) return;
  const int bg = blockIdx.y;                 // batch group of 4 (shared by block)
  const float* __restrict__ Ag = A + bg*1152;
  const float* __restrict__ bs = bsc + bg*64;

  // preload all skinning weights for this vertex pair (48 VGPRs, loop becomes load-free)
  float2 w[NJ];
#pragma unroll
  for (int n=0;n<NJ;n++) w[n] = pk[(33+n)*VH + vh];

  const float2 vt0 = pk[30*VH + vh];
  const float2 vt1 = pk[31*VH + vh];
  const float2 vt2 = pk[32*VH + vh];

  float2 vs[4][3];
#pragma unroll
  for (int q=0;q<4;q++){
    const float b0 = bs[q*16];
    vs[q][0] = make_float2(b0*vt0.x, b0*vt0.y);
    vs[q][1] = make_float2(b0*vt1.x, b0*vt1.y);
    vs[q][2] = make_float2(b0*vt2.x, b0*vt2.y);
  }
#pragma unroll
  for (int l=0;l<10;l++){
    const float2 s0 = pk[l*VH + vh];
    const float2 s1 = pk[(10+l)*VH + vh];
    const float2 s2 = pk[(20+l)*VH + vh];
#pragma unroll
    for (int q=0;q<4;q++){
      const float c = bs[q*16+1+l];
      vs[q][0].x = fmaf(c, s0.x, vs[q][0].x); vs[q][0].y = fmaf(c, s0.y, vs[q][0].y);
      vs[q][1].x = fmaf(c, s1.x, vs[q][1].x); vs[q][1].y = fmaf(c, s1.y, vs[q][1].y);
      vs[q][2].x = fmaf(c, s2.x, vs[q][2].x); vs[q][2].y = fmaf(c, s2.y, vs[q][2].y);
    }
  }

  float y[4][6];
#pragma unroll
  for (int q=0;q<4;q++)
#pragma unroll
    for (int i=0;i<6;i++) y[q][i] = 0.f;

#pragma unroll 4
  for (int n=0;n<NJ;n++){
    const float wx = w[n].x, wy = w[n].y;
#pragma unroll
    for (int q=0;q<4;q++){
      const float* __restrict__ an = Ag + n*48 + q*12;   // block-uniform -> s_load (K$-hot)
      float tt;
      tt = fmaf(an[2], vs[q][2].x, fmaf(an[1], vs[q][1].x, fmaf(an[0], vs[q][0].x, an[3])));
      y[q][0] = fmaf(wx, tt, y[q][0]);
      tt = fmaf(an[2], vs[q][2].y, fmaf(an[1], vs[q][1].y, fmaf(an[0], vs[q][0].y, an[3])));
      y[q][1] = fmaf(wy, tt, y[q][1]);
      tt = fmaf(an[6], vs[q][2].x, fmaf(an[5], vs[q][1].x, fmaf(an[4], vs[q][0].x, an[7])));
      y[q][2] = fmaf(wx, tt, y[q][2]);
      tt = fmaf(an[6], vs[q][2].y, fmaf(an[5], vs[q][1].y, fmaf(an[4], vs[q][0].y, an[7])));
      y[q][3] = fmaf(wy, tt, y[q][3]);
      tt = fmaf(an[10], vs[q][2].x, fmaf(an[9], vs[q][1].x, fmaf(an[8], vs[q][0].x, an[11])));
      y[q][4] = fmaf(wx, tt, y[q][4]);
      tt = fmaf(an[10], vs[q][2].y, fmaf(an[9], vs[q][1].y, fmaf(an[8], vs[q][0].y, an[11])));
      y[q][5] = fmaf(wy, tt, y[q][5]);
    }
  }

  const int v0 = 2*vh;
#pragma unroll
  for (int q=0;q<4;q++){
    const float t0 = bs[q*16+11], t1 = bs[q*16+12], t2 = bs[q*16+13];
    const int b = bg*4 + q;
    float2* __restrict__ o2 = (float2*)(out + (b*V + v0)*3);
    o2[0] = make_float2(y[q][0]+t0, y[q][2]+t1);
    o2[1] = make_float2(y[q][4]+t2, y[q][1]+t0);
    o2[2] = make_float2(y[q][3]+t1, y[q][5]+t2);
  }
}

extern "C" void kernel_launch(void* const* d_in, const int* in_sizes, int n_in,
                              void* d_out, int out_size, void* d_ws, size_t ws_size,
                              hipStream_t stream)
{
  const float* betas     = (const float*)d_in[0];
  const float* body_pose = (const float*)d_in[1];
  const float* go        = (const float*)d_in[2];
  const float* transl    = (const float*)d_in[3];
  const float* sdirs     = (const float*)d_in[4];
  const float* vtempl    = (const float*)d_in[5];
  const float* Jr        = (const float*)d_in[6];
  const float* lw        = (const float*)d_in[7];
  float* wsf = (float*)d_ws;
  float* out = (float*)d_out;

  hipLaunchKernelGGL(prepjr_k, dim3(PREP_BLOCKS + 24*33), dim3(256), 0, stream,
                     sdirs, vtempl, lw, Jr, wsf+PK_OFF, wsf+JT_OFF, wsf+JS_OFF);
  hipLaunchKernelGGL(batch_k, dim3(BATCH), dim3(64), 0, stream,
                     betas, body_pose, go, transl, wsf+JT_OFF, wsf+JS_OFF,
                     wsf+A_OFF, wsf+BS_OFF, out + BATCH*V*3);
  hipLaunchKernelGGL(main_k, dim3((VH+255)/256, BATCH/4), dim3(256), 0, stream,
                     wsf+A_OFF, wsf+BS_OFF, (const float2*)(wsf+PK_OFF), out);
}

// Round 6
// 245.499 us; speedup vs baseline: 1.0484x; 1.0484x over previous
//
#include <hip/hip_runtime.h>

#define BATCH 512
#define V 6890
#define NJ 24
#define VH (V/2)   // 3445 float2 per feature row

#define SD_N (V*30)
#define VT_N (V*3)
#define W_N  (V*24)
#define TOT_PK (SD_N+VT_N+W_N)   // 392730 floats
#define PREP_BLOCKS ((TOT_PK+255)/256)   // 1535

// workspace layout (float indices)
// A layout: 128 groups of 4 batches: off = (b>>2)*1152 + n*48 + (b&3)*12 + j
#define A_OFF   0
#define BS_OFF  147456     // BATCH*16 scalars {b0, b0*beta[1..10], transl[0..2], pad}
#define JT_OFF  155648     // 72  = Jr @ v_template
#define JS_OFF  155720     // 720 = Jr @ shapedirs
#define PK_OFF  156672     // transposed fp32, rows stride V:
                           //   sd row j at j*V; vt row k at (30+k)*V; W row n at (33+n)*V

__device__ const int d_par[NJ] = {-1,0,0,0,1,2,3,4,5,6,7,8,9,9,9,12,13,14,16,17,18,19,20,21};
// kinematic tree by depth level
__device__ const int lvlJ[8][5] = {{1,2,3,0,0},{4,5,6,0,0},{7,8,9,0,0},{10,11,12,13,14},
                                   {15,16,17,0,0},{18,19,0,0,0},{20,21,0,0,0},{22,23,0,0,0}};
__device__ const int lvlP[8][5] = {{0,0,0,0,0},{1,2,3,0,0},{4,5,6,0,0},{7,8,9,9,9},
                                   {12,13,14,0,0},{16,17,0,0,0},{18,19,0,0,0},{20,21,0,0,0}};
__device__ const int lvlN[8] = {3,3,3,5,3,2,2,2};

// -------- fused: transpose per-vertex data + joint-regressor contraction --------
__global__ __launch_bounds__(256) void prepjr_k(
    const float* __restrict__ sd, const float* __restrict__ vt,
    const float* __restrict__ W, const float* __restrict__ Jr,
    float* __restrict__ dst, float* __restrict__ JTo, float* __restrict__ JSo)
{
  const int bx = blockIdx.x;
  const int t = threadIdx.x;
  if (bx < PREP_BLOCKS){
    int i = bx*256 + t;
    if (i >= TOT_PK) return;
    float val;
    if (i < SD_N){ int j=i/V, v=i-j*V; val = sd[v*30+j]; }
    else if (i < SD_N+VT_N){ int o=i-SD_N; int j=o/V, v=o-j*V; val = vt[v*3+j]; }
    else { int o=i-SD_N-VT_N; int j=o/V, v=o-j*V; val = W[v*24+j]; }
    dst[i] = val;
  } else {
    const int idx = bx - PREP_BLOCKS;   // 0..791
    const int j = idx/33, c = idx-33*(idx/33);
    float acc = 0.f;
    for (int v=t; v<V; v+=256){
      float x = (c<3) ? vt[v*3+c] : sd[v*30+(c-3)];
      acc = fmaf(Jr[j*V+v], x, acc);
    }
    __shared__ float red[256];
    red[t]=acc; __syncthreads();
    for (int s=128;s>0;s>>=1){ if(t<s) red[t]+=red[t+s]; __syncthreads(); }
    if (t==0){
      if (c<3) JTo[j*3+c]=red[0];
      else {
        int ii=c-3, k=ii/10, l=ii-10*(ii/10);
        JSo[(j*3+k)*10+l] = red[0];
      }
    }
  }
}

// -------- per-batch: joints, rodrigues, level-parallel chain, A (grouped) --------
__global__ __launch_bounds__(64) void batch_k(
    const float* __restrict__ betas, const float* __restrict__ body_pose,
    const float* __restrict__ go, const float* __restrict__ transl,
    const float* __restrict__ JT, const float* __restrict__ JS,
    float* __restrict__ A, float* __restrict__ bsc, float* __restrict__ jout)
{
  const int b = blockIdx.x;
  const int t = threadIdx.x;
  __shared__ float lb[11];
  __shared__ float lJ[72];
  __shared__ float lR[NJ*9];
  __shared__ float lL[NJ*12];
  __shared__ float lW[NJ*12];
  if (t < 11) lb[t] = betas[b*11+t];
  __syncthreads();
  const float b0 = lb[0];
  for (int idx=t; idx<72; idx+=64){
    float s = JT[idx];
    #pragma unroll
    for (int l=0;l<10;l++) s = fmaf(lb[1+l], JS[idx*10+l], s);
    lJ[idx] = b0*s;
  }
  if (t==0) bsc[b*16] = b0;
  if (t>=1 && t<11) bsc[b*16+t] = b0*lb[t];
  if (t<3) bsc[b*16+11+t] = transl[b*3+t];
  if (t < NJ){
    float p0,p1,p2;
    if (t==0){ p0=go[b*3+0]; p1=go[b*3+1]; p2=go[b*3+2]; }
    else { int o=b*69+(t-1)*3; p0=body_pose[o]; p1=body_pose[o+1]; p2=body_pose[o+2]; }
    float a0=p0+1e-8f, a1=p1+1e-8f, a2=p2+1e-8f;
    float angle = sqrtf(a0*a0+a1*a1+a2*a2);
    float inv = 1.0f/angle;
    float rx=p0*inv, ry=p1*inv, rz=p2*inv;
    float sn = sinf(angle), cs = cosf(angle), mc = 1.0f-cs;
    float K[9] = {0.f,-rz,ry, rz,0.f,-rx, -ry,rx,0.f};
    float KK[9];
    #pragma unroll
    for (int r=0;r<3;r++)
      #pragma unroll
      for (int c=0;c<3;c++)
        KK[r*3+c] = K[r*3+0]*K[0+c] + K[r*3+1]*K[3+c] + K[r*3+2]*K[6+c];
    #pragma unroll
    for (int e=0;e<9;e++){
      float ident = (e==0||e==4||e==8)?1.0f:0.0f;
      lR[t*9+e] = ident + sn*K[e] + mc*KK[e];
    }
  }
  __syncthreads();
  for (int idx=t; idx<288; idx+=64){
    int j = idx/12, rc = idx-12*j, r = rc>>2, c = rc&3;
    float val;
    if (c<3) val = lR[j*9 + r*3 + c];
    else {
      int p = (j==0) ? 0 : d_par[j];
      val = (j==0) ? lJ[r] : (lJ[j*3+r] - lJ[p*3+r]);
    }
    lL[idx] = val;
  }
  __syncthreads();
  if (t<12) lW[t] = lL[t];
  __syncthreads();
  #pragma unroll
  for (int lev=0; lev<8; lev++){
    const int cnt = lvlN[lev];
    if (t < cnt*12){
      int jl = t/12, e = t-12*jl, r = e>>2, c = e&3;
      int j = lvlJ[lev][jl], p = lvlP[lev][jl];
      float s = lW[p*12+r*4+0]*lL[j*12+0+c]
              + lW[p*12+r*4+1]*lL[j*12+4+c]
              + lW[p*12+r*4+2]*lL[j*12+8+c];
      if (c==3) s += lW[p*12+r*4+3];
      lW[j*12+e] = s;
    }
    __syncthreads();
  }
  for (int idx=t; idx<72; idx+=64){
    int j=idx/3, k=idx-3*j;
    jout[b*72+idx] = lW[j*12+k*4+3];
  }
  const int g = b>>2, q = b&3;
  float* __restrict__ Ab = A + g*1152 + q*12;
  for (int idx=t; idx<288; idx+=64){
    int n=idx/12, rc=idx-12*n, r=rc>>2, c=rc&3;
    float val = lW[n*12+rc];
    if (c==3){
      val -= lW[n*12+r*4+0]*lJ[n*3+0] + lW[n*12+r*4+1]*lJ[n*3+1] + lW[n*12+r*4+2]*lJ[n*3+2];
    }
    Ab[n*48 + rc] = val;
  }
}

// -------- main LBS: 1 vertex-pair x 4 block-shared batches; w preloaded, FULL unroll --
__global__ __launch_bounds__(256) void main_k(
    const float* __restrict__ A, const float* __restrict__ bsc,
    const float2* __restrict__ pk, float* __restrict__ out)
{
  const int vh = blockIdx.x*256 + threadIdx.x;
  if (vh >= VH) return;
  const int bg = blockIdx.y;                 // batch group of 4 (shared by block)
  const float* __restrict__ Ag = A + bg*1152;
  const float* __restrict__ bs = bsc + bg*64;

  // preload all 24 skinning-weight pairs (48 VGPRs); full unroll below keeps
  // every w[n] reference a compile-time-constant register (NO dynamic indexing)
  float2 w[NJ];
#pragma unroll
  for (int n=0;n<NJ;n++) w[n] = pk[(33+n)*VH + vh];

  const float2 vt0 = pk[30*VH + vh];
  const float2 vt1 = pk[31*VH + vh];
  const float2 vt2 = pk[32*VH + vh];

  float2 vs[4][3];
#pragma unroll
  for (int q=0;q<4;q++){
    const float b0 = bs[q*16];
    vs[q][0] = make_float2(b0*vt0.x, b0*vt0.y);
    vs[q][1] = make_float2(b0*vt1.x, b0*vt1.y);
    vs[q][2] = make_float2(b0*vt2.x, b0*vt2.y);
  }
#pragma unroll
  for (int l=0;l<10;l++){
    const float2 s0 = pk[l*VH + vh];
    const float2 s1 = pk[(10+l)*VH + vh];
    const float2 s2 = pk[(20+l)*VH + vh];
#pragma unroll
    for (int q=0;q<4;q++){
      const float c = bs[q*16+1+l];
      vs[q][0].x = fmaf(c, s0.x, vs[q][0].x); vs[q][0].y = fmaf(c, s0.y, vs[q][0].y);
      vs[q][1].x = fmaf(c, s1.x, vs[q][1].x); vs[q][1].y = fmaf(c, s1.y, vs[q][1].y);
      vs[q][2].x = fmaf(c, s2.x, vs[q][2].x); vs[q][2].y = fmaf(c, s2.y, vs[q][2].y);
    }
  }

  float y[4][6];
#pragma unroll
  for (int q=0;q<4;q++)
#pragma unroll
    for (int i=0;i<6;i++) y[q][i] = 0.f;

#pragma unroll   // FULL unroll: w[n] stays in registers, loop body = FMA + K$-hot s_load
  for (int n=0;n<NJ;n++){
    const float wx = w[n].x, wy = w[n].y;
#pragma unroll
    for (int q=0;q<4;q++){
      const float* __restrict__ an = Ag + n*48 + q*12;   // block-uniform -> s_load
      float tt;
      tt = fmaf(an[2], vs[q][2].x, fmaf(an[1], vs[q][1].x, fmaf(an[0], vs[q][0].x, an[3])));
      y[q][0] = fmaf(wx, tt, y[q][0]);
      tt = fmaf(an[2], vs[q][2].y, fmaf(an[1], vs[q][1].y, fmaf(an[0], vs[q][0].y, an[3])));
      y[q][1] = fmaf(wy, tt, y[q][1]);
      tt = fmaf(an[6], vs[q][2].x, fmaf(an[5], vs[q][1].x, fmaf(an[4], vs[q][0].x, an[7])));
      y[q][2] = fmaf(wx, tt, y[q][2]);
      tt = fmaf(an[6], vs[q][2].y, fmaf(an[5], vs[q][1].y, fmaf(an[4], vs[q][0].y, an[7])));
      y[q][3] = fmaf(wy, tt, y[q][3]);
      tt = fmaf(an[10], vs[q][2].x, fmaf(an[9], vs[q][1].x, fmaf(an[8], vs[q][0].x, an[11])));
      y[q][4] = fmaf(wx, tt, y[q][4]);
      tt = fmaf(an[10], vs[q][2].y, fmaf(an[9], vs[q][1].y, fmaf(an[8], vs[q][0].y, an[11])));
      y[q][5] = fmaf(wy, tt, y[q][5]);
    }
  }

  const int v0 = 2*vh;
#pragma unroll
  for (int q=0;q<4;q++){
    const float t0 = bs[q*16+11], t1 = bs[q*16+12], t2 = bs[q*16+13];
    const int b = bg*4 + q;
    float2* __restrict__ o2 = (float2*)(out + (b*V + v0)*3);
    o2[0] = make_float2(y[q][0]+t0, y[q][2]+t1);
    o2[1] = make_float2(y[q][4]+t2, y[q][1]+t0);
    o2[2] = make_float2(y[q][3]+t1, y[q][5]+t2);
  }
}

extern "C" void kernel_launch(void* const* d_in, const int* in_sizes, int n_in,
                              void* d_out, int out_size, void* d_ws, size_t ws_size,
                              hipStream_t stream)
{
  const float* betas     = (const float*)d_in[0];
  const float* body_pose = (const float*)d_in[1];
  const float* go        = (const float*)d_in[2];
  const float* transl    = (const float*)d_in[3];
  const float* sdirs     = (const float*)d_in[4];
  const float* vtempl    = (const float*)d_in[5];
  const float* Jr        = (const float*)d_in[6];
  const float* lw        = (const float*)d_in[7];
  float* wsf = (float*)d_ws;
  float* out = (float*)d_out;

  hipLaunchKernelGGL(prepjr_k, dim3(PREP_BLOCKS + 24*33), dim3(256), 0, stream,
                     sdirs, vtempl, lw, Jr, wsf+PK_OFF, wsf+JT_OFF, wsf+JS_OFF);
  hipLaunchKernelGGL(batch_k, dim3(BATCH), dim3(64), 0, stream,
                     betas, body_pose, go, transl, wsf+JT_OFF, wsf+JS_OFF,
                     wsf+A_OFF, wsf+BS_OFF, out + BATCH*V*3);
  hipLaunchKernelGGL(main_k, dim3((VH+255)/256, BATCH/4), dim3(256), 0, stream,
                     wsf+A_OFF, wsf+BS_OFF, (const float2*)(wsf+PK_OFF), out);
}

// Round 7
// 171.068 us; speedup vs baseline: 1.5046x; 1.4351x over previous
//
#include <hip/hip_runtime.h>

#define BATCH 512
#define V 6890
#define NJ 24
#define VH (V/2)   // 3445 float2 per feature row

#define SD_N (V*30)
#define VT_N (V*3)
#define W_N  (V*24)
#define TOT_PK (SD_N+VT_N+W_N)   // 392730 floats
#define PREP_BLOCKS ((TOT_PK+255)/256)   // 1535

// workspace layout (float indices)
// A layout: 128 groups of 4 batches: off = (b>>2)*1152 + n*48 + (b&3)*12 + j
#define A_OFF   0
#define BS_OFF  147456     // BATCH*16 scalars {b0, b0*beta[1..10], transl[0..2], pad}
#define JT_OFF  155648     // 72  = Jr @ v_template
#define JS_OFF  155720     // 720 = Jr @ shapedirs
#define PK_OFF  156672     // transposed fp32, rows stride V:
                           //   sd row j at j*V; vt row k at (30+k)*V; W row n at (33+n)*V

__device__ const int d_par[NJ] = {-1,0,0,0,1,2,3,4,5,6,7,8,9,9,9,12,13,14,16,17,18,19,20,21};
// kinematic tree by depth level
__device__ const int lvlJ[8][5] = {{1,2,3,0,0},{4,5,6,0,0},{7,8,9,0,0},{10,11,12,13,14},
                                   {15,16,17,0,0},{18,19,0,0,0},{20,21,0,0,0},{22,23,0,0,0}};
__device__ const int lvlP[8][5] = {{0,0,0,0,0},{1,2,3,0,0},{4,5,6,0,0},{7,8,9,9,9},
                                   {12,13,14,0,0},{16,17,0,0,0},{18,19,0,0,0},{20,21,0,0,0}};
__device__ const int lvlN[8] = {3,3,3,5,3,2,2,2};

// -------- fused: transpose per-vertex data + joint-regressor contraction --------
__global__ __launch_bounds__(256) void prepjr_k(
    const float* __restrict__ sd, const float* __restrict__ vt,
    const float* __restrict__ W, const float* __restrict__ Jr,
    float* __restrict__ dst, float* __restrict__ JTo, float* __restrict__ JSo)
{
  const int bx = blockIdx.x;
  const int t = threadIdx.x;
  if (bx < PREP_BLOCKS){
    int i = bx*256 + t;
    if (i >= TOT_PK) return;
    float val;
    if (i < SD_N){ int j=i/V, v=i-j*V; val = sd[v*30+j]; }
    else if (i < SD_N+VT_N){ int o=i-SD_N; int j=o/V, v=o-j*V; val = vt[v*3+j]; }
    else { int o=i-SD_N-VT_N; int j=o/V, v=o-j*V; val = W[v*24+j]; }
    dst[i] = val;
  } else {
    const int idx = bx - PREP_BLOCKS;   // 0..791
    const int j = idx/33, c = idx-33*(idx/33);
    float acc = 0.f;
    for (int v=t; v<V; v+=256){
      float x = (c<3) ? vt[v*3+c] : sd[v*30+(c-3)];
      acc = fmaf(Jr[j*V+v], x, acc);
    }
    __shared__ float red[256];
    red[t]=acc; __syncthreads();
    for (int s=128;s>0;s>>=1){ if(t<s) red[t]+=red[t+s]; __syncthreads(); }
    if (t==0){
      if (c<3) JTo[j*3+c]=red[0];
      else {
        int ii=c-3, k=ii/10, l=ii-10*(ii/10);
        JSo[(j*3+k)*10+l] = red[0];
      }
    }
  }
}

// -------- per-batch: joints, rodrigues, level-parallel chain, A (grouped) --------
__global__ __launch_bounds__(64) void batch_k(
    const float* __restrict__ betas, const float* __restrict__ body_pose,
    const float* __restrict__ go, const float* __restrict__ transl,
    const float* __restrict__ JT, const float* __restrict__ JS,
    float* __restrict__ A, float* __restrict__ bsc, float* __restrict__ jout)
{
  const int b = blockIdx.x;
  const int t = threadIdx.x;
  __shared__ float lb[11];
  __shared__ float lJ[72];
  __shared__ float lR[NJ*9];
  __shared__ float lL[NJ*12];
  __shared__ float lW[NJ*12];
  if (t < 11) lb[t] = betas[b*11+t];
  __syncthreads();
  const float b0 = lb[0];
  for (int idx=t; idx<72; idx+=64){
    float s = JT[idx];
    #pragma unroll
    for (int l=0;l<10;l++) s = fmaf(lb[1+l], JS[idx*10+l], s);
    lJ[idx] = b0*s;
  }
  if (t==0) bsc[b*16] = b0;
  if (t>=1 && t<11) bsc[b*16+t] = b0*lb[t];
  if (t<3) bsc[b*16+11+t] = transl[b*3+t];
  if (t < NJ){
    float p0,p1,p2;
    if (t==0){ p0=go[b*3+0]; p1=go[b*3+1]; p2=go[b*3+2]; }
    else { int o=b*69+(t-1)*3; p0=body_pose[o]; p1=body_pose[o+1]; p2=body_pose[o+2]; }
    float a0=p0+1e-8f, a1=p1+1e-8f, a2=p2+1e-8f;
    float angle = sqrtf(a0*a0+a1*a1+a2*a2);
    float inv = 1.0f/angle;
    float rx=p0*inv, ry=p1*inv, rz=p2*inv;
    float sn = sinf(angle), cs = cosf(angle), mc = 1.0f-cs;
    float K[9] = {0.f,-rz,ry, rz,0.f,-rx, -ry,rx,0.f};
    float KK[9];
    #pragma unroll
    for (int r=0;r<3;r++)
      #pragma unroll
      for (int c=0;c<3;c++)
        KK[r*3+c] = K[r*3+0]*K[0+c] + K[r*3+1]*K[3+c] + K[r*3+2]*K[6+c];
    #pragma unroll
    for (int e=0;e<9;e++){
      float ident = (e==0||e==4||e==8)?1.0f:0.0f;
      lR[t*9+e] = ident + sn*K[e] + mc*KK[e];
    }
  }
  __syncthreads();
  for (int idx=t; idx<288; idx+=64){
    int j = idx/12, rc = idx-12*j, r = rc>>2, c = rc&3;
    float val;
    if (c<3) val = lR[j*9 + r*3 + c];
    else {
      int p = (j==0) ? 0 : d_par[j];
      val = (j==0) ? lJ[r] : (lJ[j*3+r] - lJ[p*3+r]);
    }
    lL[idx] = val;
  }
  __syncthreads();
  if (t<12) lW[t] = lL[t];
  __syncthreads();
  #pragma unroll
  for (int lev=0; lev<8; lev++){
    const int cnt = lvlN[lev];
    if (t < cnt*12){
      int jl = t/12, e = t-12*jl, r = e>>2, c = e&3;
      int j = lvlJ[lev][jl], p = lvlP[lev][jl];
      float s = lW[p*12+r*4+0]*lL[j*12+0+c]
              + lW[p*12+r*4+1]*lL[j*12+4+c]
              + lW[p*12+r*4+2]*lL[j*12+8+c];
      if (c==3) s += lW[p*12+r*4+3];
      lW[j*12+e] = s;
    }
    __syncthreads();
  }
  for (int idx=t; idx<72; idx+=64){
    int j=idx/3, k=idx-3*j;
    jout[b*72+idx] = lW[j*12+k*4+3];
  }
  const int g = b>>2, q = b&3;
  float* __restrict__ Ab = A + g*1152 + q*12;
  for (int idx=t; idx<288; idx+=64){
    int n=idx/12, rc=idx-12*n, r=rc>>2, c=rc&3;
    float val = lW[n*12+rc];
    if (c==3){
      val -= lW[n*12+r*4+0]*lJ[n*3+0] + lW[n*12+r*4+1]*lJ[n*3+1] + lW[n*12+r*4+2]*lJ[n*3+2];
    }
    Ab[n*48 + rc] = val;
  }
}

// -------- main LBS: round-3 shape, but A + bs staged in LDS (broadcast ds_read_b128) --
__global__ __launch_bounds__(256) void main_k(
    const float* __restrict__ A, const float* __restrict__ bsc,
    const float2* __restrict__ pk, float* __restrict__ out)
{
  __shared__ float lA[1152];   // 4.6 KB: this block's 4-batch A group
  __shared__ float lbs[64];
  const int t = threadIdx.x;
  const int bg = blockIdx.y;                 // batch group of 4 (shared by block)
  {
    const float4* __restrict__ src = (const float4*)(A + bg*1152);
    float4* d4 = (float4*)lA;
    for (int i=t; i<288; i+=256) d4[i] = src[i];
    if (t < 16) ((float4*)lbs)[t] = ((const float4*)(bsc + bg*64))[t];
  }
  __syncthreads();

  const int vh = blockIdx.x*256 + t;
  if (vh < VH){
    const float2 vt0 = pk[30*VH + vh];
    const float2 vt1 = pk[31*VH + vh];
    const float2 vt2 = pk[32*VH + vh];

    float2 vs[4][3];
#pragma unroll
    for (int q=0;q<4;q++){
      const float b0 = lbs[q*16];
      vs[q][0] = make_float2(b0*vt0.x, b0*vt0.y);
      vs[q][1] = make_float2(b0*vt1.x, b0*vt1.y);
      vs[q][2] = make_float2(b0*vt2.x, b0*vt2.y);
    }
#pragma unroll
    for (int l=0;l<10;l++){
      const float2 s0 = pk[l*VH + vh];
      const float2 s1 = pk[(10+l)*VH + vh];
      const float2 s2 = pk[(20+l)*VH + vh];
#pragma unroll
      for (int q=0;q<4;q++){
        const float c = lbs[q*16+1+l];
        vs[q][0].x = fmaf(c, s0.x, vs[q][0].x); vs[q][0].y = fmaf(c, s0.y, vs[q][0].y);
        vs[q][1].x = fmaf(c, s1.x, vs[q][1].x); vs[q][1].y = fmaf(c, s1.y, vs[q][1].y);
        vs[q][2].x = fmaf(c, s2.x, vs[q][2].x); vs[q][2].y = fmaf(c, s2.y, vs[q][2].y);
      }
    }

    float y[4][6];
#pragma unroll
    for (int q=0;q<4;q++)
#pragma unroll
      for (int i=0;i<6;i++) y[q][i] = 0.f;

#pragma unroll 4
    for (int n=0;n<NJ;n++){
      const float2 w2 = pk[(33+n)*VH + vh];
      const float wx = w2.x, wy = w2.y;
#pragma unroll
      for (int q=0;q<4;q++){
        // same-address broadcast ds_read_b128 x3 (16B-aligned: q*12 floats = 48 B)
        const float4 a0 = *(const float4*)(lA + n*48 + q*12 + 0);   // an[0..3]
        const float4 a1 = *(const float4*)(lA + n*48 + q*12 + 4);   // an[4..7]
        const float4 a2 = *(const float4*)(lA + n*48 + q*12 + 8);   // an[8..11]
        float tt;
        tt = fmaf(a0.z, vs[q][2].x, fmaf(a0.y, vs[q][1].x, fmaf(a0.x, vs[q][0].x, a0.w)));
        y[q][0] = fmaf(wx, tt, y[q][0]);
        tt = fmaf(a0.z, vs[q][2].y, fmaf(a0.y, vs[q][1].y, fmaf(a0.x, vs[q][0].y, a0.w)));
        y[q][1] = fmaf(wy, tt, y[q][1]);
        tt = fmaf(a1.z, vs[q][2].x, fmaf(a1.y, vs[q][1].x, fmaf(a1.x, vs[q][0].x, a1.w)));
        y[q][2] = fmaf(wx, tt, y[q][2]);
        tt = fmaf(a1.z, vs[q][2].y, fmaf(a1.y, vs[q][1].y, fmaf(a1.x, vs[q][0].y, a1.w)));
        y[q][3] = fmaf(wy, tt, y[q][3]);
        tt = fmaf(a2.z, vs[q][2].x, fmaf(a2.y, vs[q][1].x, fmaf(a2.x, vs[q][0].x, a2.w)));
        y[q][4] = fmaf(wx, tt, y[q][4]);
        tt = fmaf(a2.z, vs[q][2].y, fmaf(a2.y, vs[q][1].y, fmaf(a2.x, vs[q][0].y, a2.w)));
        y[q][5] = fmaf(wy, tt, y[q][5]);
      }
    }

    const int v0 = 2*vh;
#pragma unroll
    for (int q=0;q<4;q++){
      const float t0 = lbs[q*16+11], t1 = lbs[q*16+12], t2 = lbs[q*16+13];
      const int b = bg*4 + q;
      float2* __restrict__ o2 = (float2*)(out + (b*V + v0)*3);
      o2[0] = make_float2(y[q][0]+t0, y[q][2]+t1);
      o2[1] = make_float2(y[q][4]+t2, y[q][1]+t0);
      o2[2] = make_float2(y[q][3]+t1, y[q][5]+t2);
    }
  }
}

extern "C" void kernel_launch(void* const* d_in, const int* in_sizes, int n_in,
                              void* d_out, int out_size, void* d_ws, size_t ws_size,
                              hipStream_t stream)
{
  const float* betas     = (const float*)d_in[0];
  const float* body_pose = (const float*)d_in[1];
  const float* go        = (const float*)d_in[2];
  const float* transl    = (const float*)d_in[3];
  const float* sdirs     = (const float*)d_in[4];
  const float* vtempl    = (const float*)d_in[5];
  const float* Jr        = (const float*)d_in[6];
  const float* lw        = (const float*)d_in[7];
  float* wsf = (float*)d_ws;
  float* out = (float*)d_out;

  hipLaunchKernelGGL(prepjr_k, dim3(PREP_BLOCKS + 24*33), dim3(256), 0, stream,
                     sdirs, vtempl, lw, Jr, wsf+PK_OFF, wsf+JT_OFF, wsf+JS_OFF);
  hipLaunchKernelGGL(batch_k, dim3(BATCH), dim3(64), 0, stream,
                     betas, body_pose, go, transl, wsf+JT_OFF, wsf+JS_OFF,
                     wsf+A_OFF, wsf+BS_OFF, out + BATCH*V*3);
  hipLaunchKernelGGL(main_k, dim3((VH+255)/256, BATCH/4), dim3(256), 0, stream,
                     wsf+A_OFF, wsf+BS_OFF, (const float2*)(wsf+PK_OFF), out);
}